// Round 1
// baseline (220.876 us; speedup 1.0000x reference)
//
#include <hip/hip_runtime.h>
#include <cfloat>

#define N_NODES 2048
#define BN_TOTAL 16384   // B*N = 8*2048
#define TSTR 20          // padded LDS row stride (floats): 16 data + 4 pad, 16B-aligned

typedef float vf4 __attribute__((ext_vector_type(4)));

// Kernel 1: fused conv1x3 (x3) + sigmoid/relu + projection to si/sj.
// Mapping: c = wave id (wave-uniform -> weights in SGPRs via scalar loads),
// to = lane (0..61 active). 2 nodes per block.
// LDS tile stride padded to 20 floats: 20*to mod 32 cycles through all 8
// quad-offsets -> ds_read_b128 conflict-free (was 4-way at stride 16).
__global__ __launch_bounds__(256) void k_sisj(
    const float* __restrict__ X,
    const float* __restrict__ cw1, const float* __restrict__ cb1,
    const float* __restrict__ cw2, const float* __restrict__ cb2,
    const float* __restrict__ cw3, const float* __restrict__ cb3,
    const float* __restrict__ fcw,
    float* __restrict__ si, float* __restrict__ sj)
{
    __shared__ float tile[2][64 * TSTR];
    __shared__ float red[4][2][2];      // [wave][node][i/j]

    const int tid  = threadIdx.x;
    const int wid  = tid >> 6;
    const int lane = tid & 63;
    const int bn0  = blockIdx.x * 2;

    // Stage both X tiles (coalesced float4 from global, padded rows in LDS).
    {
        const vf4 v0 = *(const vf4*)(X + (size_t)bn0 * 1024 + tid * 4);
        const vf4 v1 = *(const vf4*)(X + (size_t)(bn0 + 1) * 1024 + tid * 4);
        const int r = tid >> 2, c = (tid & 3) * 4;
        *(vf4*)&tile[0][r * TSTR + c] = v0;
        *(vf4*)&tile[1][r * TSTR + c] = v1;
    }
    __syncthreads();

    // Wave-uniform output channel.
    const int c_u = __builtin_amdgcn_readfirstlane(wid);
    const float* __restrict__ w1 = cw1 + c_u * 48;   // (c, ci, dt) row: 48 contiguous floats
    const float* __restrict__ w2 = cw2 + c_u * 48;
    const float* __restrict__ w3 = cw3 + c_u * 48;
    const float b1 = cb1[c_u], b2 = cb2[c_u], b3 = cb3[c_u];

    const int to = lane;
    float t0 = 0.f, t1 = 0.f;

    if (to < 62) {
        // X fragments for both nodes: rows to..to+2, 16 ci each.
        vf4 xr0[3][4], xr1[3][4];
        #pragma unroll
        for (int dt = 0; dt < 3; ++dt)
            #pragma unroll
            for (int q = 0; q < 4; ++q) {
                xr0[dt][q] = *(const vf4*)&tile[0][(to + dt) * TSTR + q * 4];
                xr1[dt][q] = *(const vf4*)&tile[1][(to + dt) * TSTR + q * 4];
            }
        const float* xf0 = (const float*)xr0;   // [dt*16 + ci]
        const float* xf1 = (const float*)xr1;

        float acc0[3] = {b1, b2, b3};
        float acc1[3] = {b1, b2, b3};
        const float* __restrict__ wp[3] = {w1, w2, w3};
        #pragma unroll
        for (int k = 0; k < 3; ++k) {
            float wk[48];
            #pragma unroll
            for (int q = 0; q < 12; ++q)        // uniform address -> s_load
                *(vf4*)&wk[q * 4] = *(const vf4*)(wp[k] + q * 4);
            float a0 = acc0[k], a1 = acc1[k];
            #pragma unroll
            for (int ci = 0; ci < 16; ++ci)
                #pragma unroll
                for (int dt = 0; dt < 3; ++dt) {
                    const float w = wk[ci * 3 + dt];
                    a0 = fmaf(xf0[dt * 16 + ci], w, a0);
                    a1 = fmaf(xf1[dt * 16 + ci], w, a1);
                }
            acc0[k] = a0; acc1[k] = a1;
        }
        // temp = y1 + sigmoid(y2); t = relu(temp + y3)
        const float s0 = 1.f / (1.f + __expf(-acc0[1]));
        const float s1 = 1.f / (1.f + __expf(-acc1[1]));
        const float v0 = acc0[0] + s0 + acc0[2];
        const float v1 = acc1[0] + s1 + acc1[2];
        t0 = v0 > 0.f ? v0 : 0.f;
        t1 = v1 > 0.f ? v1 : 0.f;
    }

    // Projection: tf index = to*4 + c. wi = fcw[:248], wj = fcw[248:].
    float pi0 = 0.f, pj0 = 0.f, pi1 = 0.f, pj1 = 0.f;
    if (to < 62) {
        const float wi = fcw[to * 4 + c_u];
        const float wj = fcw[248 + to * 4 + c_u];
        pi0 = t0 * wi; pj0 = t0 * wj;
        pi1 = t1 * wi; pj1 = t1 * wj;
    }
    #pragma unroll
    for (int off = 32; off > 0; off >>= 1) {
        pi0 += __shfl_xor(pi0, off);
        pj0 += __shfl_xor(pj0, off);
        pi1 += __shfl_xor(pi1, off);
        pj1 += __shfl_xor(pj1, off);
    }
    if (lane == 0) {
        red[wid][0][0] = pi0; red[wid][0][1] = pj0;
        red[wid][1][0] = pi1; red[wid][1][1] = pj1;
    }
    __syncthreads();
    if (tid < 4) {
        const int n = tid >> 1, cmp = tid & 1;
        const float s = red[0][n][cmp] + red[1][n][cmp] + red[2][n][cmp] + red[3][n][cmp];
        float* __restrict__ dst = cmp ? sj : si;
        dst[bn0 + n] = s;
    }
}

// Kernel 2: masked leaky-relu scores + row softmax (masked entries = 0,
// included in denominator, per reference) + multiply by A.
// ONE WAVE PER ROW (4 rows/block): no LDS, no __syncthreads; all 16 vmem
// loads issued up-front, wave-level shfl reduction, then stores.
// XCD-swizzled so each XCD's L2 holds a 2 MB slab of A reused across all 8 b.
__global__ __launch_bounds__(256) void k_att(
    const float* __restrict__ A,
    const float* __restrict__ si, const float* __restrict__ sj,
    const float* __restrict__ fcb,
    float* __restrict__ out)
{
    const int blk   = blockIdx.x;                   // [0, 4096)
    const int wid   = __builtin_amdgcn_readfirstlane(threadIdx.x >> 6);
    const int lane  = threadIdx.x & 63;

    const int xcd   = blk & 7;
    const int local = blk >> 3;                     // [0, 512)
    const int rc    = local * 4 + wid;              // per-XCD row counter [0, 2048)
    const int i     = (xcd << 8) | (rc & 255);      // XCD x owns i in [256x, 256x+256)
    const int b     = rc >> 8;
    const int row   = b * N_NODES + i;

    const float cbase = si[row] + fcb[0];
    const float* __restrict__ sjb = sj + b * N_NODES;
    const float* __restrict__ Ar  = A + (size_t)i * N_NODES;

    // Issue all loads up-front: 8 float4 of A + 8 float4 of sj per lane.
    vf4 a4[8], e4[8];
    #pragma unroll
    for (int u = 0; u < 8; ++u) {
        const int j4 = lane + u * 64;
        a4[u] = ((const vf4*)Ar)[j4];
        e4[u] = ((const vf4*)sjb)[j4];              // holds sj, overwritten with exp()
    }

    float sum = 0.f;
    #pragma unroll
    for (int u = 0; u < 8; ++u) {
        vf4 e;
        #pragma unroll
        for (int q = 0; q < 4; ++q) {
            float s = cbase + e4[u][q];
            s = (s >= 0.f) ? s : 0.01f * s;         // leaky_relu
            const float at_ = (a4[u][q] != 0.f) ? s : 0.f;
            // softmax without max-subtraction: scores are O(1) here, and
            // exp(s)/sum(exp(s)) == exp(s-m)/sum(exp(s-m)) exactly in math.
            const float ev = __expf(at_);
            e[q] = ev;
            sum += ev;
        }
        e4[u] = e;
    }

    // wave allreduce (row == wave; no cross-wave traffic needed)
    #pragma unroll
    for (int off = 32; off > 0; off >>= 1) sum += __shfl_xor(sum, off);
    const float inv = 1.f / sum;

    float* __restrict__ orow = out + (size_t)row * N_NODES;
    #pragma unroll
    for (int u = 0; u < 8; ++u) {
        const int j4 = lane + u * 64;
        vf4 o;
        #pragma unroll
        for (int q = 0; q < 4; ++q)
            o[q] = a4[u][q] * (e4[u][q] * inv);
        __builtin_nontemporal_store(o, (vf4*)orow + j4);   // out never re-read: keep A in L2
    }
}

extern "C" void kernel_launch(void* const* d_in, const int* in_sizes, int n_in,
                              void* d_out, int out_size, void* d_ws, size_t ws_size,
                              hipStream_t stream)
{
    const float* X   = (const float*)d_in[0];
    const float* A   = (const float*)d_in[1];
    const float* cw1 = (const float*)d_in[2];
    const float* cb1 = (const float*)d_in[3];
    const float* cw2 = (const float*)d_in[4];
    const float* cb2 = (const float*)d_in[5];
    const float* cw3 = (const float*)d_in[6];
    const float* cb3 = (const float*)d_in[7];
    const float* fcw = (const float*)d_in[8];
    const float* fcb = (const float*)d_in[9];
    float* out = (float*)d_out;

    float* si = (float*)d_ws;          // 16384 floats
    float* sj = si + BN_TOTAL;         // 16384 floats

    hipLaunchKernelGGL(k_sisj, dim3(BN_TOTAL / 2), dim3(256), 0, stream,
                       X, cw1, cb1, cw2, cb2, cw3, cb3, fcw, si, sj);
    hipLaunchKernelGGL(k_att, dim3(BN_TOTAL / 4), dim3(256), 0, stream,
                       A, si, sj, fcb, out);
}